// Round 4
// baseline (658.352 us; speedup 1.0000x reference)
//
#include <hip/hip_runtime.h>
#include <hip/hip_bf16.h>
#include <math.h>

typedef unsigned short ushort_t;
typedef __attribute__((ext_vector_type(8))) __bf16 bf16x8;
typedef __attribute__((ext_vector_type(4))) float f32x4;
typedef __attribute__((ext_vector_type(4))) unsigned int u32x4;

#define E_DIM 512
#define HEADS 8
#define HD 64
#define SEQ 2048
#define NROWS 8192        // B * SEQ
#define NEGF (-1e30f)

static __device__ __forceinline__ unsigned short f2b(float f) {
  unsigned int x;
  __builtin_memcpy(&x, &f, 4);
  x += 0x7fffu + ((x >> 16) & 1u);   // round-to-nearest-even
  return (unsigned short)(x >> 16);
}

// ---------------- weight transpose + cast: WT[n][k] = bf16(W[k][n]), 512x512 ----------------
__launch_bounds__(256)
__global__ void transpose512(const float* __restrict__ in, ushort_t* __restrict__ out) {
  __shared__ float tile[32 * 33];
  int t = threadIdx.x;
  int tx = t & 31, ty = t >> 5;            // 32 x 8
  int n0 = blockIdx.x * 32, k0 = blockIdx.y * 32;
#pragma unroll
  for (int i = 0; i < 4; ++i) {
    int k = ty + i * 8;
    tile[k * 33 + tx] = in[(k0 + k) * E_DIM + n0 + tx];
  }
  __syncthreads();
#pragma unroll
  for (int i = 0; i < 4; ++i) {
    int n = ty + i * 8;
    out[(n0 + n) * E_DIM + k0 + tx] = f2b(tile[tx * 33 + n]);
  }
}

// ---------------- mask pack: bits[(b*SEQ+q)*64 + k/32] = AND of kv & sparse ----------------
__launch_bounds__(256)
__global__ void pack_mask(const int* __restrict__ kvm, const int* __restrict__ sp,
                          unsigned int* __restrict__ bits) {
  int wIdx = blockIdx.x * 256 + threadIdx.x;   // 4*2048*64 = 524288 words
  int b = wIdx >> 17;
  int q = (wIdx >> 6) & 2047;
  int kw = wIdx & 63;
  const int* sprow = sp + (((size_t)b * SEQ + q) << 11) + (kw << 5);
  const int* kvrow = kvm + (b << 11) + (kw << 5);
  unsigned int m = 0;
#pragma unroll
  for (int j = 0; j < 32; ++j)
    if (sprow[j] != 0 && kvrow[j] != 0) m |= (1u << j);
  bits[wIdx] = m;
}

// ---------------- V transpose: vp[b][k][h*64+d] -> Vt[((b*8+h)*64+d)*2048 + k] ----------------
__launch_bounds__(256)
__global__ void transposeV(const ushort_t* __restrict__ vp, ushort_t* __restrict__ Vt) {
  __shared__ ushort_t tile[64][72];   // [k][d], +8 pad
  int t = threadIdx.x;
  int k0 = blockIdx.x * 64, h = blockIdx.y, b = blockIdx.z;
#pragma unroll
  for (int it = 0; it < 2; ++it) {
    int row = it * 32 + (t >> 3);       // k in tile
    int col = (t & 7) * 8;              // d
    *(u32x4*)&tile[row][col] =
        *(const u32x4*)&vp[(size_t)(b * SEQ + k0 + row) * E_DIM + h * HD + col];
  }
  __syncthreads();
#pragma unroll
  for (int it = 0; it < 2; ++it) {
    int d = it * 32 + (t >> 3);
    int kc = (t & 7) * 8;
    union { ushort_t u[8]; u32x4 v; } o;
#pragma unroll
    for (int j = 0; j < 8; ++j) o.u[j] = tile[kc + j][d];
    *(u32x4*)&Vt[((size_t)(b * HEADS + h) * HD + d) * SEQ + k0 + kc] = o.v;
  }
}

// ---------------- LayerNorm: wave per row (512 fp32 elems, 8/lane), bf16 out ----------------
__launch_bounds__(256)
__global__ void ln_kernel(const float* __restrict__ x, const float* __restrict__ g,
                          const float* __restrict__ bb, ushort_t* __restrict__ y) {
  int t = threadIdx.x, w = t >> 6, l = t & 63;
  int row = blockIdx.x * 4 + w;
  f32x4 x0 = *(const f32x4*)&x[row * E_DIM + l * 8];
  f32x4 x1 = *(const f32x4*)&x[row * E_DIM + l * 8 + 4];
  float xf[8];
  float s = 0.f, ss = 0.f;
#pragma unroll
  for (int j = 0; j < 8; ++j) {
    xf[j] = (j < 4) ? x0[j] : x1[j - 4];
    s += xf[j];
    ss += xf[j] * xf[j];
  }
#pragma unroll
  for (int off = 32; off > 0; off >>= 1) {
    s += __shfl_xor(s, off);
    ss += __shfl_xor(ss, off);
  }
  float mu = s * (1.f / 512.f);
  float var = fmaxf(ss * (1.f / 512.f) - mu * mu, 0.f);
  float rs = rsqrtf(var + 1e-5f);
  f32x4 g0 = *(const f32x4*)&g[l * 8];
  f32x4 g1 = *(const f32x4*)&g[l * 8 + 4];
  f32x4 b0 = *(const f32x4*)&bb[l * 8];
  f32x4 b1 = *(const f32x4*)&bb[l * 8 + 4];
#pragma unroll
  for (int j = 0; j < 8; ++j) {
    float gv = (j < 4) ? g0[j] : g1[j - 4];
    float bv = (j < 4) ? b0[j] : b1[j - 4];
    y[row * E_DIM + l * 8 + j] = f2b((xf[j] - mu) * rs * gv + bv);
  }
}

// ---------------- GEMM: C[M,512] = ((A @ WT^T) + bias) * scale (bf16 in, OUT_T out) ---------
// WT is (N,K) row-major bf16 (pre-transposed). 64x64 tile, BK=32, 256 thr / 4 waves.
template <typename OUT_T>
__launch_bounds__(256)
__global__ void gemm_bias(const ushort_t* __restrict__ A, const ushort_t* __restrict__ WT,
                          const float* __restrict__ bias, OUT_T* __restrict__ C, float scale) {
  __shared__ ushort_t lA[64 * 32];
  __shared__ ushort_t lB[64 * 32];
  int t = threadIdx.x, w = t >> 6, l = t & 63;
  int quad = l >> 4, l15 = l & 15;
  int m0 = blockIdx.x * 64, n0 = blockIdx.y * 64;

  f32x4 acc[4] = {};
  const ushort_t* ga = A + (m0 + (t >> 2)) * E_DIM + (t & 3) * 8;
  const ushort_t* gb = WT + (n0 + (t >> 2)) * E_DIM + (t & 3) * 8;
  int sidx = (t >> 2) * 32 + (t & 3) * 8;

  for (int kk = 0; kk < E_DIM; kk += 32) {
    *(u32x4*)&lA[sidx] = *(const u32x4*)(ga + kk);
    *(u32x4*)&lB[sidx] = *(const u32x4*)(gb + kk);
    __syncthreads();
    bf16x8 a = *(const bf16x8*)&lA[(w * 16 + l15) * 32 + quad * 8];
#pragma unroll
    for (int nt = 0; nt < 4; ++nt) {
      bf16x8 b = *(const bf16x8*)&lB[(nt * 16 + l15) * 32 + quad * 8];
      acc[nt] = __builtin_amdgcn_mfma_f32_16x16x32_bf16(a, b, acc[nt], 0, 0, 0);
    }
    __syncthreads();
  }
#pragma unroll
  for (int nt = 0; nt < 4; ++nt) {
    int col = n0 + nt * 16 + l15;
    float bv = bias[col];
#pragma unroll
    for (int r = 0; r < 4; ++r) {
      int rowm = m0 + w * 16 + quad * 4 + r;   // C/D: col=lane&15, row=quad*4+r (m89)
      float val = (acc[nt][r] + bv) * scale;
      if constexpr (sizeof(OUT_T) == 2)
        C[rowm * E_DIM + col] = f2b(val);
      else
        C[rowm * E_DIM + col] = val;
    }
  }
}

// ---------------- flash attention: block per (b, h, 64-row q-tile) ----------------
// Qp pre-scaled by 0.125. Vt is [b][h][d][k]. bits = packed (kv & sparse) mask.
__launch_bounds__(256)
__global__ void attn_kernel(const ushort_t* __restrict__ Qp, const ushort_t* __restrict__ Kp,
                            const ushort_t* __restrict__ Vt, const unsigned int* __restrict__ bits,
                            ushort_t* __restrict__ ctx) {
  __shared__ ushort_t sQ[64 * 64];
  __shared__ ushort_t sK[64 * 64];
  __shared__ ushort_t sVt[64 * 64];   // [d][k]
  __shared__ ushort_t sP[64 * 72];    // +8 pad: cuts scalar-write conflicts
  int t = threadIdx.x, w = t >> 6, l = t & 63;
  int quad = l >> 4, l15 = l & 15;
  int q0 = blockIdx.x * 64;
  int h = blockIdx.y;
  int b = blockIdx.z;
  int bh = b * HEADS + h;

  // stage Q tile (64 rows x 64 d)
#pragma unroll
  for (int it = 0; it < 2; ++it) {
    int row = it * 32 + (t >> 3), d = (t & 7) * 8;
    *(u32x4*)&sQ[row * 64 + d] =
        *(const u32x4*)&Qp[(size_t)(b * SEQ + q0 + row) * E_DIM + h * HD + d];
  }

  float m[4], lsum[4];
  f32x4 o[4] = {};
#pragma unroll
  for (int r = 0; r < 4; ++r) { m[r] = NEGF; lsum[r] = 0.f; }

  for (int kt = 0; kt < 32; ++kt) {
    int k0 = kt * 64;
    __syncthreads();   // previous QK^T/PV reads of sK/sVt done
#pragma unroll
    for (int it = 0; it < 2; ++it) {
      int row = it * 32 + (t >> 3), c = (t & 7) * 8;
      *(u32x4*)&sK[row * 64 + c] =
          *(const u32x4*)&Kp[(size_t)(b * SEQ + k0 + row) * E_DIM + h * HD + c];
      *(u32x4*)&sVt[row * 64 + c] =
          *(const u32x4*)&Vt[((size_t)bh * HD + row) * SEQ + k0 + c];
    }
    __syncthreads();

    // S = Q K^T  (64x64, wave w owns rows w*16..+16); Q pre-scaled
    f32x4 s[4] = {};
#pragma unroll
    for (int ks = 0; ks < 2; ++ks) {
      bf16x8 a = *(const bf16x8*)&sQ[(w * 16 + l15) * 64 + ks * 32 + quad * 8];
#pragma unroll
      for (int nt = 0; nt < 4; ++nt) {
        bf16x8 bfr = *(const bf16x8*)&sK[(nt * 16 + l15) * 64 + ks * 32 + quad * 8];
        s[nt] = __builtin_amdgcn_mfma_f32_16x16x32_bf16(a, bfr, s[nt], 0, 0, 0);
      }
    }

    // online softmax; mask from packed bits (one uint2 per q-row per tile, broadcast)
#pragma unroll
    for (int r = 0; r < 4; ++r) {
      int qrow = q0 + w * 16 + quad * 4 + r;
      uint2 wm = *(const uint2*)&bits[((size_t)(b * SEQ + qrow) << 6) + kt * 2];
      float sv[4];
      bool ok[4];
      float vm = NEGF;
#pragma unroll
      for (int nt = 0; nt < 4; ++nt) {
        int idx = nt * 16 + l15;
        unsigned int word = (idx & 32) ? wm.y : wm.x;
        ok[nt] = (word >> (idx & 31)) & 1u;
        sv[nt] = s[nt][r];
        if (ok[nt]) vm = fmaxf(vm, sv[nt]);
      }
#pragma unroll
      for (int off = 1; off < 16; off <<= 1) vm = fmaxf(vm, __shfl_xor(vm, off));
      float mnew = fmaxf(m[r], vm);
      float alpha = __expf(m[r] - mnew);   // both NEGF -> exp(0)=1; NEGF->finite -> 0
      float ps = 0.f;
#pragma unroll
      for (int nt = 0; nt < 4; ++nt) {
        float pv = ok[nt] ? __expf(sv[nt] - mnew) : 0.f;
        ps += pv;
        sP[(w * 16 + quad * 4 + r) * 72 + nt * 16 + l15] = f2b(pv);
      }
#pragma unroll
      for (int off = 1; off < 16; off <<= 1) ps += __shfl_xor(ps, off);
      lsum[r] = lsum[r] * alpha + ps;
      m[r] = mnew;
#pragma unroll
      for (int nt = 0; nt < 4; ++nt) o[nt][r] *= alpha;
    }
    __syncthreads();   // sP visible before PV

    // O += P @ V : both fragments now contiguous ds_read_b128
#pragma unroll
    for (int ks = 0; ks < 2; ++ks) {
      bf16x8 a = *(const bf16x8*)&sP[(w * 16 + l15) * 72 + ks * 32 + quad * 8];
#pragma unroll
      for (int nt = 0; nt < 4; ++nt) {
        bf16x8 bfr = *(const bf16x8*)&sVt[(nt * 16 + l15) * 64 + ks * 32 + quad * 8];
        o[nt] = __builtin_amdgcn_mfma_f32_16x16x32_bf16(a, bfr, o[nt], 0, 0, 0);
      }
    }
  }

  // epilogue: normalize; rows with no valid key -> 0
#pragma unroll
  for (int r = 0; r < 4; ++r) {
    float inv = (m[r] > -0.9e30f && lsum[r] > 0.f) ? 1.f / lsum[r] : 0.f;
    int qrow = q0 + w * 16 + quad * 4 + r;
#pragma unroll
    for (int nt = 0; nt < 4; ++nt)
      ctx[(size_t)(b * SEQ + qrow) * E_DIM + h * HD + nt * 16 + l15] = f2b(o[nt][r] * inv);
  }
}

// ---------------- launch ----------------
// fp32 in/out, bf16 internals. ws = 20 MiB: bufA(8) bufB(8) WT(2) bits(2).
// d_out (16 MB fp32) doubles as two 8 MB bf16 slots dlo/dhi.
// Liveness schedule (single stream, race-free):
//   WT <- transpose(W*); bits <- pack_mask
//   qn  = LN(query)        -> dlo
//   kvn = LN(key_value)    -> bufA
//   qp  = (qn@WTq+bq)*.125 -> dhi
//   kp  = kvn@WTk+bk       -> dlo   [qn dead]
//   vp  = kvn@WTv+bv       -> bufB
//   Vt  = transposeV(vp)   -> bufA  [kvn dead]
//   ctx = attn(qp,kp,Vt)   -> bufB  [vp dead]
//   out = ctx@WTo+bo       -> d_out [qp/kp dead]
extern "C" void kernel_launch(void* const* d_in, const int* in_sizes, int n_in,
                              void* d_out, int out_size, void* d_ws, size_t ws_size,
                              hipStream_t stream) {
  const float* query     = (const float*)d_in[0];
  const float* key_value = (const float*)d_in[1];
  const int*   kv_mask   = (const int*)d_in[2];
  const int*   sp_mask   = (const int*)d_in[3];
  const float* ln_q_g  = (const float*)d_in[4];
  const float* ln_q_b  = (const float*)d_in[5];
  const float* ln_kv_g = (const float*)d_in[6];
  const float* ln_kv_b = (const float*)d_in[7];
  const float* Wq = (const float*)d_in[8];
  const float* bq = (const float*)d_in[9];
  const float* Wk = (const float*)d_in[10];
  const float* bk = (const float*)d_in[11];
  const float* Wv = (const float*)d_in[12];
  const float* bv = (const float*)d_in[13];
  const float* Wo = (const float*)d_in[14];
  const float* bo = (const float*)d_in[15];

  const size_t NB = (size_t)NROWS * E_DIM;       // 4M bf16 elements = 8 MiB
  char* ws = (char*)d_ws;
  ushort_t* bufA = (ushort_t*)ws;                // kvn -> Vt
  ushort_t* bufB = bufA + NB;                    // vp -> ctx
  ushort_t* WTq  = bufB + NB;                    // 4 x 512x512 bf16 = 2 MiB
  ushort_t* WTk = WTq + E_DIM * E_DIM;
  ushort_t* WTv = WTk + E_DIM * E_DIM;
  ushort_t* WTo = WTv + E_DIM * E_DIM;
  unsigned int* bits = (unsigned int*)(WTo + E_DIM * E_DIM);  // 2 MiB

  ushort_t* dlo = (ushort_t*)d_out;              // qn, then kp
  ushort_t* dhi = dlo + NB;                      // qp

  transpose512<<<dim3(16, 16), 256, 0, stream>>>(Wq, WTq);
  transpose512<<<dim3(16, 16), 256, 0, stream>>>(Wk, WTk);
  transpose512<<<dim3(16, 16), 256, 0, stream>>>(Wv, WTv);
  transpose512<<<dim3(16, 16), 256, 0, stream>>>(Wo, WTo);
  pack_mask<<<2048, 256, 0, stream>>>(kv_mask, sp_mask, bits);

  ln_kernel<<<2048, 256, 0, stream>>>(query, ln_q_g, ln_q_b, dlo);        // qn
  ln_kernel<<<2048, 256, 0, stream>>>(key_value, ln_kv_g, ln_kv_b, bufA); // kvn

  gemm_bias<ushort_t><<<dim3(128, 8), 256, 0, stream>>>(dlo, WTq, bq, dhi, 0.125f); // qp
  gemm_bias<ushort_t><<<dim3(128, 8), 256, 0, stream>>>(bufA, WTk, bk, dlo, 1.f);   // kp
  gemm_bias<ushort_t><<<dim3(128, 8), 256, 0, stream>>>(bufA, WTv, bv, bufB, 1.f);  // vp

  transposeV<<<dim3(32, HEADS, 4), 256, 0, stream>>>(bufB, bufA);          // Vt

  attn_kernel<<<dim3(32, HEADS, 4), 256, 0, stream>>>(dhi, dlo, bufA, bits, bufB);

  gemm_bias<float><<<dim3(128, 8), 256, 0, stream>>>(bufB, WTo, bo, (float*)d_out, 1.f);
}

// Round 5
// 405.514 us; speedup vs baseline: 1.6235x; 1.6235x over previous
//
#include <hip/hip_runtime.h>
#include <hip/hip_bf16.h>
#include <math.h>

typedef unsigned short ushort_t;
typedef __attribute__((ext_vector_type(8))) __bf16 bf16x8;
typedef __attribute__((ext_vector_type(4))) float f32x4;
typedef __attribute__((ext_vector_type(4))) unsigned int u32x4;

#define E_DIM 512
#define HEADS 8
#define HD 64
#define SEQ 2048
#define NROWS 8192        // B * SEQ
#define NEGF (-1e30f)

static __device__ __forceinline__ unsigned short f2b(float f) {
  unsigned int x;
  __builtin_memcpy(&x, &f, 4);
  x += 0x7fffu + ((x >> 16) & 1u);   // round-to-nearest-even
  return (unsigned short)(x >> 16);
}

// ---------------- weight transpose + cast: WT[n][k] = bf16(W[k][n]), 512x512 ----------------
__launch_bounds__(256)
__global__ void transpose512(const float* __restrict__ in, ushort_t* __restrict__ out) {
  __shared__ float tile[32 * 33];
  int t = threadIdx.x;
  int tx = t & 31, ty = t >> 5;            // 32 x 8
  int n0 = blockIdx.x * 32, k0 = blockIdx.y * 32;
#pragma unroll
  for (int i = 0; i < 4; ++i) {
    int k = ty + i * 8;
    tile[k * 33 + tx] = in[(k0 + k) * E_DIM + n0 + tx];
  }
  __syncthreads();
#pragma unroll
  for (int i = 0; i < 4; ++i) {
    int n = ty + i * 8;
    out[(n0 + n) * E_DIM + k0 + tx] = f2b(tile[tx * 33 + n]);
  }
}

// ---------------- mask pack (wave-cooperative ballot, coalesced) ----------------
// wave per q-row; iter it: lane l tests k = it*64+l; __ballot -> uint64 word.
// Layout identical to what attn reads as uint2: bits64[row*32 + kt].
__launch_bounds__(256)
__global__ void pack_mask(const int* __restrict__ kvm, const int* __restrict__ sp,
                          unsigned long long* __restrict__ bits) {
  int t = threadIdx.x, w = t >> 6, l = t & 63;
  int row = blockIdx.x * 4 + w;            // 8192 rows (b*2048+q)
  int b = row >> 11;
  const int* sprow = sp + ((size_t)row << 11);
  const int* kvrow = kvm + (b << 11);
  unsigned long long* out = bits + ((size_t)row << 5);
#pragma unroll 4
  for (int it = 0; it < 32; ++it) {
    int k = it * 64 + l;
    unsigned long long m = __ballot(sprow[k] != 0 && kvrow[k] != 0);
    if (l == 0) out[it] = m;
  }
}

// ---------------- V transpose: vp[b][k][h*64+d] -> Vt[((b*8+h)*64+d)*2048 + k] ----------------
__launch_bounds__(256)
__global__ void transposeV(const ushort_t* __restrict__ vp, ushort_t* __restrict__ Vt) {
  __shared__ ushort_t tile[64][72];   // [k][d], +8 pad
  int t = threadIdx.x;
  int k0 = blockIdx.x * 64, h = blockIdx.y, b = blockIdx.z;
#pragma unroll
  for (int it = 0; it < 2; ++it) {
    int row = it * 32 + (t >> 3);       // k in tile
    int col = (t & 7) * 8;              // d
    *(u32x4*)&tile[row][col] =
        *(const u32x4*)&vp[(size_t)(b * SEQ + k0 + row) * E_DIM + h * HD + col];
  }
  __syncthreads();
#pragma unroll
  for (int it = 0; it < 2; ++it) {
    int d = it * 32 + (t >> 3);
    int kc = (t & 7) * 8;
    union { ushort_t u[8]; u32x4 v; } o;
#pragma unroll
    for (int j = 0; j < 8; ++j) o.u[j] = tile[kc + j][d];
    *(u32x4*)&Vt[((size_t)(b * HEADS + h) * HD + d) * SEQ + k0 + kc] = o.v;
  }
}

// ---------------- LayerNorm: wave per row (512 fp32 elems, 8/lane), bf16 out ----------------
__launch_bounds__(256)
__global__ void ln_kernel(const float* __restrict__ x, const float* __restrict__ g,
                          const float* __restrict__ bb, ushort_t* __restrict__ y) {
  int t = threadIdx.x, w = t >> 6, l = t & 63;
  int row = blockIdx.x * 4 + w;
  f32x4 x0 = *(const f32x4*)&x[row * E_DIM + l * 8];
  f32x4 x1 = *(const f32x4*)&x[row * E_DIM + l * 8 + 4];
  float xf[8];
  float s = 0.f, ss = 0.f;
#pragma unroll
  for (int j = 0; j < 8; ++j) {
    xf[j] = (j < 4) ? x0[j] : x1[j - 4];
    s += xf[j];
    ss += xf[j] * xf[j];
  }
#pragma unroll
  for (int off = 32; off > 0; off >>= 1) {
    s += __shfl_xor(s, off);
    ss += __shfl_xor(ss, off);
  }
  float mu = s * (1.f / 512.f);
  float var = fmaxf(ss * (1.f / 512.f) - mu * mu, 0.f);
  float rs = rsqrtf(var + 1e-5f);
  f32x4 g0 = *(const f32x4*)&g[l * 8];
  f32x4 g1 = *(const f32x4*)&g[l * 8 + 4];
  f32x4 b0 = *(const f32x4*)&bb[l * 8];
  f32x4 b1 = *(const f32x4*)&bb[l * 8 + 4];
#pragma unroll
  for (int j = 0; j < 8; ++j) {
    float gv = (j < 4) ? g0[j] : g1[j - 4];
    float bv = (j < 4) ? b0[j] : b1[j - 4];
    y[row * E_DIM + l * 8 + j] = f2b((xf[j] - mu) * rs * gv + bv);
  }
}

// ---------------- GEMM: C[M,512] = ((A @ WT^T) + bias) * scale (bf16 in, OUT_T out) ---------
// WT is (N,K) row-major bf16 (pre-transposed). 64x64 tile, BK=32, 256 thr / 4 waves.
template <typename OUT_T>
__launch_bounds__(256)
__global__ void gemm_bias(const ushort_t* __restrict__ A, const ushort_t* __restrict__ WT,
                          const float* __restrict__ bias, OUT_T* __restrict__ C, float scale) {
  __shared__ ushort_t lA[64 * 32];
  __shared__ ushort_t lB[64 * 32];
  int t = threadIdx.x, w = t >> 6, l = t & 63;
  int quad = l >> 4, l15 = l & 15;
  int m0 = blockIdx.x * 64, n0 = blockIdx.y * 64;

  f32x4 acc[4] = {};
  const ushort_t* ga = A + (m0 + (t >> 2)) * E_DIM + (t & 3) * 8;
  const ushort_t* gb = WT + (n0 + (t >> 2)) * E_DIM + (t & 3) * 8;
  int sidx = (t >> 2) * 32 + (t & 3) * 8;

  for (int kk = 0; kk < E_DIM; kk += 32) {
    *(u32x4*)&lA[sidx] = *(const u32x4*)(ga + kk);
    *(u32x4*)&lB[sidx] = *(const u32x4*)(gb + kk);
    __syncthreads();
    bf16x8 a = *(const bf16x8*)&lA[(w * 16 + l15) * 32 + quad * 8];
#pragma unroll
    for (int nt = 0; nt < 4; ++nt) {
      bf16x8 b = *(const bf16x8*)&lB[(nt * 16 + l15) * 32 + quad * 8];
      acc[nt] = __builtin_amdgcn_mfma_f32_16x16x32_bf16(a, b, acc[nt], 0, 0, 0);
    }
    __syncthreads();
  }
#pragma unroll
  for (int nt = 0; nt < 4; ++nt) {
    int col = n0 + nt * 16 + l15;
    float bv = bias[col];
#pragma unroll
    for (int r = 0; r < 4; ++r) {
      int rowm = m0 + w * 16 + quad * 4 + r;   // C/D: col=lane&15, row=quad*4+r (m89)
      float val = (acc[nt][r] + bv) * scale;
      if constexpr (sizeof(OUT_T) == 2)
        C[rowm * E_DIM + col] = f2b(val);
      else
        C[rowm * E_DIM + col] = val;
    }
  }
}

// ---------------- flash attention: block per (b, h, 64-row q-tile) ----------------
// Qp pre-scaled by 0.125. Vt is [b][h][d][k]. bits = packed (kv & sparse) mask.
__launch_bounds__(256)
__global__ void attn_kernel(const ushort_t* __restrict__ Qp, const ushort_t* __restrict__ Kp,
                            const ushort_t* __restrict__ Vt, const unsigned int* __restrict__ bits,
                            ushort_t* __restrict__ ctx) {
  __shared__ ushort_t sQ[64 * 64];
  __shared__ ushort_t sK[64 * 64];
  __shared__ ushort_t sVt[64 * 64];   // [d][k]
  __shared__ ushort_t sP[64 * 72];    // +8 pad: cuts scalar-write conflicts
  int t = threadIdx.x, w = t >> 6, l = t & 63;
  int quad = l >> 4, l15 = l & 15;
  int q0 = blockIdx.x * 64;
  int h = blockIdx.y;
  int b = blockIdx.z;
  int bh = b * HEADS + h;

  // stage Q tile (64 rows x 64 d)
#pragma unroll
  for (int it = 0; it < 2; ++it) {
    int row = it * 32 + (t >> 3), d = (t & 7) * 8;
    *(u32x4*)&sQ[row * 64 + d] =
        *(const u32x4*)&Qp[(size_t)(b * SEQ + q0 + row) * E_DIM + h * HD + d];
  }

  float m[4], lsum[4];
  f32x4 o[4] = {};
#pragma unroll
  for (int r = 0; r < 4; ++r) { m[r] = NEGF; lsum[r] = 0.f; }

  for (int kt = 0; kt < 32; ++kt) {
    int k0 = kt * 64;
    __syncthreads();   // previous QK^T/PV reads of sK/sVt done
#pragma unroll
    for (int it = 0; it < 2; ++it) {
      int row = it * 32 + (t >> 3), c = (t & 7) * 8;
      *(u32x4*)&sK[row * 64 + c] =
          *(const u32x4*)&Kp[(size_t)(b * SEQ + k0 + row) * E_DIM + h * HD + c];
      *(u32x4*)&sVt[row * 64 + c] =
          *(const u32x4*)&Vt[((size_t)bh * HD + row) * SEQ + k0 + c];
    }
    __syncthreads();

    // S = Q K^T  (64x64, wave w owns rows w*16..+16); Q pre-scaled
    f32x4 s[4] = {};
#pragma unroll
    for (int ks = 0; ks < 2; ++ks) {
      bf16x8 a = *(const bf16x8*)&sQ[(w * 16 + l15) * 64 + ks * 32 + quad * 8];
#pragma unroll
      for (int nt = 0; nt < 4; ++nt) {
        bf16x8 bfr = *(const bf16x8*)&sK[(nt * 16 + l15) * 64 + ks * 32 + quad * 8];
        s[nt] = __builtin_amdgcn_mfma_f32_16x16x32_bf16(a, bfr, s[nt], 0, 0, 0);
      }
    }

    // online softmax; mask from packed bits (one uint2 per q-row per tile, broadcast)
#pragma unroll
    for (int r = 0; r < 4; ++r) {
      int qrow = q0 + w * 16 + quad * 4 + r;
      uint2 wm = *(const uint2*)&bits[((size_t)(b * SEQ + qrow) << 6) + kt * 2];
      float sv[4];
      bool ok[4];
      float vm = NEGF;
#pragma unroll
      for (int nt = 0; nt < 4; ++nt) {
        int idx = nt * 16 + l15;
        unsigned int word = (idx & 32) ? wm.y : wm.x;
        ok[nt] = (word >> (idx & 31)) & 1u;
        sv[nt] = s[nt][r];
        if (ok[nt]) vm = fmaxf(vm, sv[nt]);
      }
#pragma unroll
      for (int off = 1; off < 16; off <<= 1) vm = fmaxf(vm, __shfl_xor(vm, off));
      float mnew = fmaxf(m[r], vm);
      float alpha = __expf(m[r] - mnew);   // both NEGF -> exp(0)=1; NEGF->finite -> 0
      float ps = 0.f;
#pragma unroll
      for (int nt = 0; nt < 4; ++nt) {
        float pv = ok[nt] ? __expf(sv[nt] - mnew) : 0.f;
        ps += pv;
        sP[(w * 16 + quad * 4 + r) * 72 + nt * 16 + l15] = f2b(pv);
      }
#pragma unroll
      for (int off = 1; off < 16; off <<= 1) ps += __shfl_xor(ps, off);
      lsum[r] = lsum[r] * alpha + ps;
      m[r] = mnew;
#pragma unroll
      for (int nt = 0; nt < 4; ++nt) o[nt][r] *= alpha;
    }
    __syncthreads();   // sP visible before PV

    // O += P @ V : both fragments contiguous ds_read_b128
#pragma unroll
    for (int ks = 0; ks < 2; ++ks) {
      bf16x8 a = *(const bf16x8*)&sP[(w * 16 + l15) * 72 + ks * 32 + quad * 8];
#pragma unroll
      for (int nt = 0; nt < 4; ++nt) {
        bf16x8 bfr = *(const bf16x8*)&sVt[(nt * 16 + l15) * 64 + ks * 32 + quad * 8];
        o[nt] = __builtin_amdgcn_mfma_f32_16x16x32_bf16(a, bfr, o[nt], 0, 0, 0);
      }
    }
  }

  // epilogue: normalize; rows with no valid key -> 0
#pragma unroll
  for (int r = 0; r < 4; ++r) {
    float inv = (m[r] > -0.9e30f && lsum[r] > 0.f) ? 1.f / lsum[r] : 0.f;
    int qrow = q0 + w * 16 + quad * 4 + r;
#pragma unroll
    for (int nt = 0; nt < 4; ++nt)
      ctx[(size_t)(b * SEQ + qrow) * E_DIM + h * HD + nt * 16 + l15] = f2b(o[nt][r] * inv);
  }
}

// ---------------- launch ----------------
// fp32 in/out, bf16 internals. ws = 20 MiB: bufA(8) bufB(8) WT(2) bits(2).
// d_out (16 MB fp32) doubles as two 8 MB bf16 slots dlo/dhi.
// Liveness schedule (single stream, race-free):
//   WT <- transpose(W*); bits <- pack_mask
//   qn  = LN(query)        -> dlo
//   kvn = LN(key_value)    -> bufA
//   qp  = (qn@WTq+bq)*.125 -> dhi
//   kp  = kvn@WTk+bk       -> dlo   [qn dead]
//   vp  = kvn@WTv+bv       -> bufB
//   Vt  = transposeV(vp)   -> bufA  [kvn dead]
//   ctx = attn(qp,kp,Vt)   -> bufB  [vp dead]
//   out = ctx@WTo+bo       -> d_out [qp/kp dead]
extern "C" void kernel_launch(void* const* d_in, const int* in_sizes, int n_in,
                              void* d_out, int out_size, void* d_ws, size_t ws_size,
                              hipStream_t stream) {
  const float* query     = (const float*)d_in[0];
  const float* key_value = (const float*)d_in[1];
  const int*   kv_mask   = (const int*)d_in[2];
  const int*   sp_mask   = (const int*)d_in[3];
  const float* ln_q_g  = (const float*)d_in[4];
  const float* ln_q_b  = (const float*)d_in[5];
  const float* ln_kv_g = (const float*)d_in[6];
  const float* ln_kv_b = (const float*)d_in[7];
  const float* Wq = (const float*)d_in[8];
  const float* bq = (const float*)d_in[9];
  const float* Wk = (const float*)d_in[10];
  const float* bk = (const float*)d_in[11];
  const float* Wv = (const float*)d_in[12];
  const float* bv = (const float*)d_in[13];
  const float* Wo = (const float*)d_in[14];
  const float* bo = (const float*)d_in[15];

  const size_t NB = (size_t)NROWS * E_DIM;       // 4M bf16 elements = 8 MiB
  char* ws = (char*)d_ws;
  ushort_t* bufA = (ushort_t*)ws;                // kvn -> Vt
  ushort_t* bufB = bufA + NB;                    // vp -> ctx
  ushort_t* WTq  = bufB + NB;                    // 4 x 512x512 bf16 = 2 MiB
  ushort_t* WTk = WTq + E_DIM * E_DIM;
  ushort_t* WTv = WTk + E_DIM * E_DIM;
  ushort_t* WTo = WTv + E_DIM * E_DIM;
  unsigned long long* bits = (unsigned long long*)(WTo + E_DIM * E_DIM);  // 2 MiB

  ushort_t* dlo = (ushort_t*)d_out;              // qn, then kp
  ushort_t* dhi = dlo + NB;                      // qp

  transpose512<<<dim3(16, 16), 256, 0, stream>>>(Wq, WTq);
  transpose512<<<dim3(16, 16), 256, 0, stream>>>(Wk, WTk);
  transpose512<<<dim3(16, 16), 256, 0, stream>>>(Wv, WTv);
  transpose512<<<dim3(16, 16), 256, 0, stream>>>(Wo, WTo);
  pack_mask<<<2048, 256, 0, stream>>>(kv_mask, sp_mask, bits);

  ln_kernel<<<2048, 256, 0, stream>>>(query, ln_q_g, ln_q_b, dlo);        // qn
  ln_kernel<<<2048, 256, 0, stream>>>(key_value, ln_kv_g, ln_kv_b, bufA); // kvn

  gemm_bias<ushort_t><<<dim3(128, 8), 256, 0, stream>>>(dlo, WTq, bq, dhi, 0.125f); // qp
  gemm_bias<ushort_t><<<dim3(128, 8), 256, 0, stream>>>(bufA, WTk, bk, dlo, 1.f);   // kp
  gemm_bias<ushort_t><<<dim3(128, 8), 256, 0, stream>>>(bufA, WTv, bv, bufB, 1.f);  // vp

  transposeV<<<dim3(32, HEADS, 4), 256, 0, stream>>>(bufB, bufA);          // Vt

  attn_kernel<<<dim3(32, HEADS, 4), 256, 0, stream>>>(dhi, dlo, bufA,
                                                      (const unsigned int*)bits, bufB);

  gemm_bias<float><<<dim3(128, 8), 256, 0, stream>>>(bufB, WTo, bo, (float*)d_out, 1.f);
}

// Round 6
// 361.158 us; speedup vs baseline: 1.8229x; 1.1228x over previous
//
#include <hip/hip_runtime.h>
#include <hip/hip_bf16.h>
#include <math.h>

typedef unsigned short ushort_t;
typedef __attribute__((ext_vector_type(8))) __bf16 bf16x8;
typedef __attribute__((ext_vector_type(4))) float f32x4;
typedef __attribute__((ext_vector_type(4))) unsigned int u32x4;

#define E_DIM 512
#define HEADS 8
#define HD 64
#define SEQ 2048
#define NROWS 8192        // B * SEQ
#define NEGF (-1e30f)

static __device__ __forceinline__ unsigned short f2b(float f) {
  unsigned int x;
  __builtin_memcpy(&x, &f, 4);
  x += 0x7fffu + ((x >> 16) & 1u);   // round-to-nearest-even
  return (unsigned short)(x >> 16);
}

// XOR-swizzled LDS index for 64-col bf16 tiles (16B chunks).
// addr(row, col) = row*64 + ((chunk ^ (row&7))<<3) + (col&7), chunk = col>>3.
// Breaks the 128B-row-stride 16-way bank aliasing (m136: 2-way is free).
static __device__ __forceinline__ int swz(int row, int col) {
  return row * 64 + ((((col >> 3) ^ (row & 7)) & 7) << 3) + (col & 7);
}

// ---------------- weight transpose + cast: WT[n][k] = bf16(W[k][n]), 512x512 ----------------
__launch_bounds__(256)
__global__ void transpose512(const float* __restrict__ in, ushort_t* __restrict__ out) {
  __shared__ float tile[32 * 33];
  int t = threadIdx.x;
  int tx = t & 31, ty = t >> 5;            // 32 x 8
  int n0 = blockIdx.x * 32, k0 = blockIdx.y * 32;
#pragma unroll
  for (int i = 0; i < 4; ++i) {
    int k = ty + i * 8;
    tile[k * 33 + tx] = in[(k0 + k) * E_DIM + n0 + tx];
  }
  __syncthreads();
#pragma unroll
  for (int i = 0; i < 4; ++i) {
    int n = ty + i * 8;
    out[(n0 + n) * E_DIM + k0 + tx] = f2b(tile[tx * 33 + n]);
  }
}

// ---------------- mask pack (wave-cooperative ballot, coalesced) ----------------
__launch_bounds__(256)
__global__ void pack_mask(const int* __restrict__ kvm, const int* __restrict__ sp,
                          unsigned long long* __restrict__ bits) {
  int t = threadIdx.x, w = t >> 6, l = t & 63;
  int row = blockIdx.x * 4 + w;            // 8192 rows (b*2048+q)
  int b = row >> 11;
  const int* sprow = sp + ((size_t)row << 11);
  const int* kvrow = kvm + (b << 11);
  unsigned long long* out = bits + ((size_t)row << 5);
#pragma unroll 4
  for (int it = 0; it < 32; ++it) {
    int k = it * 64 + l;
    unsigned long long m = __ballot(sprow[k] != 0 && kvrow[k] != 0);
    if (l == 0) out[it] = m;
  }
}

// ---------------- V transpose: vp[b][k][h*64+d] -> Vt[((b*8+h)*64+d)*2048 + k] ----------------
__launch_bounds__(256)
__global__ void transposeV(const ushort_t* __restrict__ vp, ushort_t* __restrict__ Vt) {
  __shared__ ushort_t tile[64][72];   // [k][d], +8 pad
  int t = threadIdx.x;
  int k0 = blockIdx.x * 64, h = blockIdx.y, b = blockIdx.z;
#pragma unroll
  for (int it = 0; it < 2; ++it) {
    int row = it * 32 + (t >> 3);       // k in tile
    int col = (t & 7) * 8;              // d
    *(u32x4*)&tile[row][col] =
        *(const u32x4*)&vp[(size_t)(b * SEQ + k0 + row) * E_DIM + h * HD + col];
  }
  __syncthreads();
#pragma unroll
  for (int it = 0; it < 2; ++it) {
    int d = it * 32 + (t >> 3);
    int kc = (t & 7) * 8;
    union { ushort_t u[8]; u32x4 v; } o;
#pragma unroll
    for (int j = 0; j < 8; ++j) o.u[j] = tile[kc + j][d];
    *(u32x4*)&Vt[((size_t)(b * HEADS + h) * HD + d) * SEQ + k0 + kc] = o.v;
  }
}

// ---------------- LayerNorm: wave per row (512 fp32 elems, 8/lane), bf16 out ----------------
__launch_bounds__(256)
__global__ void ln_kernel(const float* __restrict__ x, const float* __restrict__ g,
                          const float* __restrict__ bb, ushort_t* __restrict__ y) {
  int t = threadIdx.x, w = t >> 6, l = t & 63;
  int row = blockIdx.x * 4 + w;
  f32x4 x0 = *(const f32x4*)&x[row * E_DIM + l * 8];
  f32x4 x1 = *(const f32x4*)&x[row * E_DIM + l * 8 + 4];
  float xf[8];
  float s = 0.f, ss = 0.f;
#pragma unroll
  for (int j = 0; j < 8; ++j) {
    xf[j] = (j < 4) ? x0[j] : x1[j - 4];
    s += xf[j];
    ss += xf[j] * xf[j];
  }
#pragma unroll
  for (int off = 32; off > 0; off >>= 1) {
    s += __shfl_xor(s, off);
    ss += __shfl_xor(ss, off);
  }
  float mu = s * (1.f / 512.f);
  float var = fmaxf(ss * (1.f / 512.f) - mu * mu, 0.f);
  float rs = rsqrtf(var + 1e-5f);
  f32x4 g0 = *(const f32x4*)&g[l * 8];
  f32x4 g1 = *(const f32x4*)&g[l * 8 + 4];
  f32x4 b0 = *(const f32x4*)&bb[l * 8];
  f32x4 b1 = *(const f32x4*)&bb[l * 8 + 4];
#pragma unroll
  for (int j = 0; j < 8; ++j) {
    float gv = (j < 4) ? g0[j] : g1[j - 4];
    float bv = (j < 4) ? b0[j] : b1[j - 4];
    y[row * E_DIM + l * 8 + j] = f2b((xf[j] - mu) * rs * gv + bv);
  }
}

// ---------------- GEMM: C[M,512] = ((A @ WT^T) + bias) * scale (bf16 in, OUT_T out) ---------
// 128x64 tile, BK=64, swizzled LDS, 4 waves in 2x2 grid (each 64m x 32n, 4x2 acc).
template <typename OUT_T>
__launch_bounds__(256)
__global__ void gemm_bias(const ushort_t* __restrict__ A, const ushort_t* __restrict__ WT,
                          const float* __restrict__ bias, OUT_T* __restrict__ C, float scale) {
  __shared__ ushort_t lA[128 * 64];
  __shared__ ushort_t lB[64 * 64];
  int t = threadIdx.x, w = t >> 6, l = t & 63;
  int quad = l >> 4, l15 = l & 15;
  int wm = w >> 1, wn = w & 1;
  int m0 = blockIdx.x * 128, n0 = blockIdx.y * 64;

  f32x4 acc[4][2] = {};

  for (int kk = 0; kk < E_DIM; kk += 64) {
    __syncthreads();   // previous-iter fragment reads done
#pragma unroll
    for (int i = 0; i < 4; ++i) {        // stage A: 128 rows x 8 chunks
      int idx = i * 256 + t;
      int row = idx >> 3, ch = idx & 7;
      *(u32x4*)&lA[swz(row, ch * 8)] = *(const u32x4*)&A[(m0 + row) * E_DIM + kk + ch * 8];
    }
#pragma unroll
    for (int i = 0; i < 2; ++i) {        // stage B: 64 rows x 8 chunks
      int idx = i * 256 + t;
      int row = idx >> 3, ch = idx & 7;
      *(u32x4*)&lB[swz(row, ch * 8)] = *(const u32x4*)&WT[(n0 + row) * E_DIM + kk + ch * 8];
    }
    __syncthreads();
#pragma unroll
    for (int ks = 0; ks < 2; ++ks) {
      bf16x8 af[4], bf[2];
#pragma unroll
      for (int mt = 0; mt < 4; ++mt)
        af[mt] = *(const bf16x8*)&lA[swz(wm * 64 + mt * 16 + l15, ks * 32 + quad * 8)];
#pragma unroll
      for (int nt = 0; nt < 2; ++nt)
        bf[nt] = *(const bf16x8*)&lB[swz(wn * 32 + nt * 16 + l15, ks * 32 + quad * 8)];
#pragma unroll
      for (int mt = 0; mt < 4; ++mt)
#pragma unroll
        for (int nt = 0; nt < 2; ++nt)
          acc[mt][nt] = __builtin_amdgcn_mfma_f32_16x16x32_bf16(af[mt], bf[nt], acc[mt][nt], 0, 0, 0);
    }
  }
#pragma unroll
  for (int nt = 0; nt < 2; ++nt) {
    int col = n0 + wn * 32 + nt * 16 + l15;
    float bv = bias[col];
#pragma unroll
    for (int mt = 0; mt < 4; ++mt) {
#pragma unroll
      for (int r = 0; r < 4; ++r) {
        int rowm = m0 + wm * 64 + mt * 16 + quad * 4 + r;   // C/D: col=lane&15, row=quad*4+r
        float val = (acc[mt][nt][r] + bv) * scale;
        if constexpr (sizeof(OUT_T) == 2)
          C[rowm * E_DIM + col] = f2b(val);
        else
          C[rowm * E_DIM + col] = val;
      }
    }
  }
}

// ---------------- flash attention: block per (b, h, 64-row q-tile) ----------------
// Qp pre-scaled by 0.125. Vt is [b][h][d][k]. bits = packed (kv & sparse) mask.
// All LDS tiles XOR-swizzled (conflict-free fragment reads).
__launch_bounds__(256)
__global__ void attn_kernel(const ushort_t* __restrict__ Qp, const ushort_t* __restrict__ Kp,
                            const ushort_t* __restrict__ Vt, const unsigned int* __restrict__ bits,
                            ushort_t* __restrict__ ctx) {
  __shared__ ushort_t sQ[64 * 64];
  __shared__ ushort_t sK[64 * 64];
  __shared__ ushort_t sVt[64 * 64];   // [d][k]
  __shared__ ushort_t sP[64 * 64];
  int t = threadIdx.x, w = t >> 6, l = t & 63;
  int quad = l >> 4, l15 = l & 15;
  int q0 = blockIdx.x * 64;
  int h = blockIdx.y;
  int b = blockIdx.z;
  int bh = b * HEADS + h;

  // stage Q tile (64 rows x 64 d), swizzled
#pragma unroll
  for (int it = 0; it < 2; ++it) {
    int row = it * 32 + (t >> 3), ch = t & 7;
    *(u32x4*)&sQ[swz(row, ch * 8)] =
        *(const u32x4*)&Qp[(size_t)(b * SEQ + q0 + row) * E_DIM + h * HD + ch * 8];
  }

  float m[4], lsum[4];
  f32x4 o[4] = {};
#pragma unroll
  for (int r = 0; r < 4; ++r) { m[r] = NEGF; lsum[r] = 0.f; }

  for (int kt = 0; kt < 32; ++kt) {
    int k0 = kt * 64;
    __syncthreads();   // previous QK^T/PV reads of sK/sVt done
#pragma unroll
    for (int it = 0; it < 2; ++it) {
      int row = it * 32 + (t >> 3), ch = t & 7;
      *(u32x4*)&sK[swz(row, ch * 8)] =
          *(const u32x4*)&Kp[(size_t)(b * SEQ + k0 + row) * E_DIM + h * HD + ch * 8];
      *(u32x4*)&sVt[swz(row, ch * 8)] =
          *(const u32x4*)&Vt[((size_t)bh * HD + row) * SEQ + k0 + ch * 8];
    }
    __syncthreads();

    // S = Q K^T  (64x64, wave w owns rows w*16..+16); Q pre-scaled
    f32x4 s[4] = {};
#pragma unroll
    for (int ks = 0; ks < 2; ++ks) {
      bf16x8 a = *(const bf16x8*)&sQ[swz(w * 16 + l15, ks * 32 + quad * 8)];
#pragma unroll
      for (int nt = 0; nt < 4; ++nt) {
        bf16x8 bfr = *(const bf16x8*)&sK[swz(nt * 16 + l15, ks * 32 + quad * 8)];
        s[nt] = __builtin_amdgcn_mfma_f32_16x16x32_bf16(a, bfr, s[nt], 0, 0, 0);
      }
    }

    // online softmax; mask from packed bits (one uint2 per q-row per tile, broadcast)
#pragma unroll
    for (int r = 0; r < 4; ++r) {
      int qrow = q0 + w * 16 + quad * 4 + r;
      uint2 wm = *(const uint2*)&bits[((size_t)(b * SEQ + qrow) << 6) + kt * 2];
      float sv[4];
      bool ok[4];
      float vm = NEGF;
#pragma unroll
      for (int nt = 0; nt < 4; ++nt) {
        int idx = nt * 16 + l15;
        unsigned int word = (idx & 32) ? wm.y : wm.x;
        ok[nt] = (word >> (idx & 31)) & 1u;
        sv[nt] = s[nt][r];
        if (ok[nt]) vm = fmaxf(vm, sv[nt]);
      }
#pragma unroll
      for (int off = 1; off < 16; off <<= 1) vm = fmaxf(vm, __shfl_xor(vm, off));
      float mnew = fmaxf(m[r], vm);
      float alpha = __expf(m[r] - mnew);   // both NEGF -> exp(0)=1; NEGF->finite -> 0
      float ps = 0.f;
      int prow = w * 16 + quad * 4 + r;
#pragma unroll
      for (int nt = 0; nt < 4; ++nt) {
        float pv = ok[nt] ? __expf(sv[nt] - mnew) : 0.f;
        ps += pv;
        sP[swz(prow, nt * 16 + l15)] = f2b(pv);
      }
#pragma unroll
      for (int off = 1; off < 16; off <<= 1) ps += __shfl_xor(ps, off);
      lsum[r] = lsum[r] * alpha + ps;
      m[r] = mnew;
#pragma unroll
      for (int nt = 0; nt < 4; ++nt) o[nt][r] *= alpha;
    }
    __syncthreads();   // sP visible before PV

    // O += P @ V : both fragments contiguous, swizzled (conflict-free)
#pragma unroll
    for (int ks = 0; ks < 2; ++ks) {
      bf16x8 a = *(const bf16x8*)&sP[swz(w * 16 + l15, ks * 32 + quad * 8)];
#pragma unroll
      for (int nt = 0; nt < 4; ++nt) {
        bf16x8 bfr = *(const bf16x8*)&sVt[swz(nt * 16 + l15, ks * 32 + quad * 8)];
        o[nt] = __builtin_amdgcn_mfma_f32_16x16x32_bf16(a, bfr, o[nt], 0, 0, 0);
      }
    }
  }

  // epilogue: normalize; rows with no valid key -> 0
#pragma unroll
  for (int r = 0; r < 4; ++r) {
    float inv = (m[r] > -0.9e30f && lsum[r] > 0.f) ? 1.f / lsum[r] : 0.f;
    int qrow = q0 + w * 16 + quad * 4 + r;
#pragma unroll
    for (int nt = 0; nt < 4; ++nt)
      ctx[(size_t)(b * SEQ + qrow) * E_DIM + h * HD + nt * 16 + l15] = f2b(o[nt][r] * inv);
  }
}

// ---------------- launch ----------------
// fp32 in/out, bf16 internals. ws = 20 MiB: bufA(8) bufB(8) WT(2) bits(2).
// d_out (16 MB fp32) doubles as two 8 MB bf16 slots dlo/dhi.
// Liveness schedule (single stream, race-free):
//   WT <- transpose(W*); bits <- pack_mask
//   qn  = LN(query)        -> dlo
//   kvn = LN(key_value)    -> bufA
//   qp  = (qn@WTq+bq)*.125 -> dhi
//   kp  = kvn@WTk+bk       -> dlo   [qn dead]
//   vp  = kvn@WTv+bv       -> bufB
//   Vt  = transposeV(vp)   -> bufA  [kvn dead]
//   ctx = attn(qp,kp,Vt)   -> bufB  [vp dead]
//   out = ctx@WTo+bo       -> d_out [qp/kp dead]
extern "C" void kernel_launch(void* const* d_in, const int* in_sizes, int n_in,
                              void* d_out, int out_size, void* d_ws, size_t ws_size,
                              hipStream_t stream) {
  const float* query     = (const float*)d_in[0];
  const float* key_value = (const float*)d_in[1];
  const int*   kv_mask   = (const int*)d_in[2];
  const int*   sp_mask   = (const int*)d_in[3];
  const float* ln_q_g  = (const float*)d_in[4];
  const float* ln_q_b  = (const float*)d_in[5];
  const float* ln_kv_g = (const float*)d_in[6];
  const float* ln_kv_b = (const float*)d_in[7];
  const float* Wq = (const float*)d_in[8];
  const float* bq = (const float*)d_in[9];
  const float* Wk = (const float*)d_in[10];
  const float* bk = (const float*)d_in[11];
  const float* Wv = (const float*)d_in[12];
  const float* bv = (const float*)d_in[13];
  const float* Wo = (const float*)d_in[14];
  const float* bo = (const float*)d_in[15];

  const size_t NB = (size_t)NROWS * E_DIM;       // 4M bf16 elements = 8 MiB
  char* ws = (char*)d_ws;
  ushort_t* bufA = (ushort_t*)ws;                // kvn -> Vt
  ushort_t* bufB = bufA + NB;                    // vp -> ctx
  ushort_t* WTq  = bufB + NB;                    // 4 x 512x512 bf16 = 2 MiB
  ushort_t* WTk = WTq + E_DIM * E_DIM;
  ushort_t* WTv = WTk + E_DIM * E_DIM;
  ushort_t* WTo = WTv + E_DIM * E_DIM;
  unsigned long long* bits = (unsigned long long*)(WTo + E_DIM * E_DIM);  // 2 MiB

  ushort_t* dlo = (ushort_t*)d_out;              // qn, then kp
  ushort_t* dhi = dlo + NB;                      // qp

  transpose512<<<dim3(16, 16), 256, 0, stream>>>(Wq, WTq);
  transpose512<<<dim3(16, 16), 256, 0, stream>>>(Wk, WTk);
  transpose512<<<dim3(16, 16), 256, 0, stream>>>(Wv, WTv);
  transpose512<<<dim3(16, 16), 256, 0, stream>>>(Wo, WTo);
  pack_mask<<<2048, 256, 0, stream>>>(kv_mask, sp_mask, bits);

  ln_kernel<<<2048, 256, 0, stream>>>(query, ln_q_g, ln_q_b, dlo);        // qn
  ln_kernel<<<2048, 256, 0, stream>>>(key_value, ln_kv_g, ln_kv_b, bufA); // kvn

  gemm_bias<ushort_t><<<dim3(64, 8), 256, 0, stream>>>(dlo, WTq, bq, dhi, 0.125f); // qp
  gemm_bias<ushort_t><<<dim3(64, 8), 256, 0, stream>>>(bufA, WTk, bk, dlo, 1.f);   // kp
  gemm_bias<ushort_t><<<dim3(64, 8), 256, 0, stream>>>(bufA, WTv, bv, bufB, 1.f);  // vp

  transposeV<<<dim3(32, HEADS, 4), 256, 0, stream>>>(bufB, bufA);          // Vt

  attn_kernel<<<dim3(32, HEADS, 4), 256, 0, stream>>>(dhi, dlo, bufA,
                                                      (const unsigned int*)bits, bufB);

  gemm_bias<float><<<dim3(64, 8), 256, 0, stream>>>(bufB, WTo, bo, (float*)d_out, 1.f);
}

// Round 7
// 326.939 us; speedup vs baseline: 2.0137x; 1.1047x over previous
//
#include <hip/hip_runtime.h>
#include <hip/hip_bf16.h>
#include <math.h>

typedef unsigned short ushort_t;
typedef __attribute__((ext_vector_type(8))) __bf16 bf16x8;
typedef __attribute__((ext_vector_type(4))) float f32x4;
typedef __attribute__((ext_vector_type(4))) unsigned int u32x4;

#define E_DIM 512
#define HEADS 8
#define HD 64
#define SEQ 2048
#define NROWS 8192        // B * SEQ
#define NEGF (-1e30f)

static __device__ __forceinline__ unsigned short f2b(float f) {
  unsigned int x;
  __builtin_memcpy(&x, &f, 4);
  x += 0x7fffu + ((x >> 16) & 1u);   // round-to-nearest-even
  return (unsigned short)(x >> 16);
}

// XOR-swizzled LDS index for 64-col bf16 tiles (16B chunks).
static __device__ __forceinline__ int swz(int row, int col) {
  return row * 64 + ((((col >> 3) ^ (row & 7)) & 7) << 3) + (col & 7);
}

// ---------------- fused weight transpose: WT[z][n][k] = bf16(W_z[k][n]) ----------------
__launch_bounds__(256)
__global__ void transposeW4(const float* __restrict__ W0, const float* __restrict__ W1,
                            const float* __restrict__ W2, const float* __restrict__ W3,
                            ushort_t* __restrict__ out) {
  int z = blockIdx.z;
  const float* in = (z == 0) ? W0 : (z == 1) ? W1 : (z == 2) ? W2 : W3;
  ushort_t* o = out + (size_t)z * E_DIM * E_DIM;
  __shared__ float tile[32 * 33];
  int t = threadIdx.x;
  int tx = t & 31, ty = t >> 5;            // 32 x 8
  int n0 = blockIdx.x * 32, k0 = blockIdx.y * 32;
#pragma unroll
  for (int i = 0; i < 4; ++i) {
    int k = ty + i * 8;
    tile[k * 33 + tx] = in[(k0 + k) * E_DIM + n0 + tx];
  }
  __syncthreads();
#pragma unroll
  for (int i = 0; i < 4; ++i) {
    int n = ty + i * 8;
    o[(n0 + n) * E_DIM + k0 + tx] = f2b(tile[tx * 33 + n]);
  }
}

// ---------------- mask pack (wave-cooperative ballot, coalesced) ----------------
__launch_bounds__(256)
__global__ void pack_mask(const int* __restrict__ kvm, const int* __restrict__ sp,
                          unsigned long long* __restrict__ bits) {
  int t = threadIdx.x, w = t >> 6, l = t & 63;
  int row = blockIdx.x * 4 + w;            // 8192 rows (b*2048+q)
  int b = row >> 11;
  const int* sprow = sp + ((size_t)row << 11);
  const int* kvrow = kvm + (b << 11);
  unsigned long long* out = bits + ((size_t)row << 5);
#pragma unroll 4
  for (int it = 0; it < 32; ++it) {
    int k = it * 64 + l;
    unsigned long long m = __ballot(sprow[k] != 0 && kvrow[k] != 0);
    if (l == 0) out[it] = m;
  }
}

// ---------------- V transpose: vp[b][k][h*64+d] -> Vt[((b*8+h)*64+d)*2048 + k] ----------------
__launch_bounds__(256)
__global__ void transposeV(const ushort_t* __restrict__ vp, ushort_t* __restrict__ Vt) {
  __shared__ ushort_t tile[64][72];   // [k][d], +8 pad
  int t = threadIdx.x;
  int k0 = blockIdx.x * 64, h = blockIdx.y, b = blockIdx.z;
#pragma unroll
  for (int it = 0; it < 2; ++it) {
    int row = it * 32 + (t >> 3);       // k in tile
    int col = (t & 7) * 8;              // d
    *(u32x4*)&tile[row][col] =
        *(const u32x4*)&vp[(size_t)(b * SEQ + k0 + row) * E_DIM + h * HD + col];
  }
  __syncthreads();
#pragma unroll
  for (int it = 0; it < 2; ++it) {
    int d = it * 32 + (t >> 3);
    int kc = (t & 7) * 8;
    union { ushort_t u[8]; u32x4 v; } o;
#pragma unroll
    for (int j = 0; j < 8; ++j) o.u[j] = tile[kc + j][d];
    *(u32x4*)&Vt[((size_t)(b * HEADS + h) * HD + d) * SEQ + k0 + kc] = o.v;
  }
}

// ---------------- fused LayerNorm (both tensors): wave per row ----------------
__launch_bounds__(256)
__global__ void ln2_kernel(const float* __restrict__ xq, const float* __restrict__ xkv,
                           const float* __restrict__ gq, const float* __restrict__ bq,
                           const float* __restrict__ gkv, const float* __restrict__ bkv,
                           ushort_t* __restrict__ yq, ushort_t* __restrict__ ykv) {
  int which = blockIdx.y;
  const float* x = which ? xkv : xq;
  const float* g = which ? gkv : gq;
  const float* bb = which ? bkv : bq;
  ushort_t* y = which ? ykv : yq;
  int t = threadIdx.x, w = t >> 6, l = t & 63;
  int row = blockIdx.x * 4 + w;
  f32x4 x0 = *(const f32x4*)&x[row * E_DIM + l * 8];
  f32x4 x1 = *(const f32x4*)&x[row * E_DIM + l * 8 + 4];
  float xf[8];
  float s = 0.f, ss = 0.f;
#pragma unroll
  for (int j = 0; j < 8; ++j) {
    xf[j] = (j < 4) ? x0[j] : x1[j - 4];
    s += xf[j];
    ss += xf[j] * xf[j];
  }
#pragma unroll
  for (int off = 32; off > 0; off >>= 1) {
    s += __shfl_xor(s, off);
    ss += __shfl_xor(ss, off);
  }
  float mu = s * (1.f / 512.f);
  float var = fmaxf(ss * (1.f / 512.f) - mu * mu, 0.f);
  float rs = rsqrtf(var + 1e-5f);
  f32x4 g0 = *(const f32x4*)&g[l * 8];
  f32x4 g1 = *(const f32x4*)&g[l * 8 + 4];
  f32x4 b0 = *(const f32x4*)&bb[l * 8];
  f32x4 b1 = *(const f32x4*)&bb[l * 8 + 4];
#pragma unroll
  for (int j = 0; j < 8; ++j) {
    float gv = (j < 4) ? g0[j] : g1[j - 4];
    float bv = (j < 4) ? b0[j] : b1[j - 4];
    y[row * E_DIM + l * 8 + j] = f2b((xf[j] - mu) * rs * gv + bv);
  }
}

// ---------------- GEMM: C[M,512] = ((A @ WT^T) + bias) * scale (bf16 in, OUT_T out) ---------
// 128x64 tile, BK=64, swizzled LDS, 4 waves in 2x2 grid (each 64m x 32n, 4x2 acc).
template <typename OUT_T>
__launch_bounds__(256)
__global__ void gemm_bias(const ushort_t* __restrict__ A, const ushort_t* __restrict__ WT,
                          const float* __restrict__ bias, OUT_T* __restrict__ C, float scale) {
  __shared__ ushort_t lA[128 * 64];
  __shared__ ushort_t lB[64 * 64];
  int t = threadIdx.x, w = t >> 6, l = t & 63;
  int quad = l >> 4, l15 = l & 15;
  int wm = w >> 1, wn = w & 1;
  int m0 = blockIdx.x * 128, n0 = blockIdx.y * 64;

  f32x4 acc[4][2] = {};

  for (int kk = 0; kk < E_DIM; kk += 64) {
    __syncthreads();   // previous-iter fragment reads done
#pragma unroll
    for (int i = 0; i < 4; ++i) {        // stage A: 128 rows x 8 chunks
      int idx = i * 256 + t;
      int row = idx >> 3, ch = idx & 7;
      *(u32x4*)&lA[swz(row, ch * 8)] = *(const u32x4*)&A[(m0 + row) * E_DIM + kk + ch * 8];
    }
#pragma unroll
    for (int i = 0; i < 2; ++i) {        // stage B: 64 rows x 8 chunks
      int idx = i * 256 + t;
      int row = idx >> 3, ch = idx & 7;
      *(u32x4*)&lB[swz(row, ch * 8)] = *(const u32x4*)&WT[(n0 + row) * E_DIM + kk + ch * 8];
    }
    __syncthreads();
#pragma unroll
    for (int ks = 0; ks < 2; ++ks) {
      bf16x8 af[4], bf[2];
#pragma unroll
      for (int mt = 0; mt < 4; ++mt)
        af[mt] = *(const bf16x8*)&lA[swz(wm * 64 + mt * 16 + l15, ks * 32 + quad * 8)];
#pragma unroll
      for (int nt = 0; nt < 2; ++nt)
        bf[nt] = *(const bf16x8*)&lB[swz(wn * 32 + nt * 16 + l15, ks * 32 + quad * 8)];
#pragma unroll
      for (int mt = 0; mt < 4; ++mt)
#pragma unroll
        for (int nt = 0; nt < 2; ++nt)
          acc[mt][nt] = __builtin_amdgcn_mfma_f32_16x16x32_bf16(af[mt], bf[nt], acc[mt][nt], 0, 0, 0);
    }
  }
#pragma unroll
  for (int nt = 0; nt < 2; ++nt) {
    int col = n0 + wn * 32 + nt * 16 + l15;
    float bv = bias[col];
#pragma unroll
    for (int mt = 0; mt < 4; ++mt) {
#pragma unroll
      for (int r = 0; r < 4; ++r) {
        int rowm = m0 + wm * 64 + mt * 16 + quad * 4 + r;   // C/D: col=lane&15, row=quad*4+r
        float val = (acc[mt][nt][r] + bv) * scale;
        if constexpr (sizeof(OUT_T) == 2)
          C[rowm * E_DIM + col] = f2b(val);
        else
          C[rowm * E_DIM + col] = val;
      }
    }
  }
}

// ---------------- flash attention, transposed-S scheme ----------------
// Block per (b, h, 64-row q-tile). Qp pre-scaled by 0.125. Vt is [b][h][d][k].
// S^T = K·Q^T: lane holds 16 scores of ONE q (q = w*16+l15, k = nt*16+quad*4+r)
// -> softmax reductions are in-lane + 2 cross-quad shuffles; state is per-lane scalar.
// PV as O^T = V^T·P^T: A-frag sVt[d][k], B-frag sP[q][k], both contiguous swizzled.
__launch_bounds__(256)
__global__ void attn_kernel(const ushort_t* __restrict__ Qp, const ushort_t* __restrict__ Kp,
                            const ushort_t* __restrict__ Vt,
                            const unsigned long long* __restrict__ bits,
                            ushort_t* __restrict__ ctx) {
  __shared__ ushort_t sQ[64 * 64];
  __shared__ ushort_t sK[64 * 64];
  __shared__ ushort_t sVt[64 * 64];   // [d][k]
  __shared__ ushort_t sP[64 * 64];    // [q][k]
  int t = threadIdx.x, w = t >> 6, l = t & 63;
  int quad = l >> 4, l15 = l & 15;
  int q0 = blockIdx.x * 64;
  int h = blockIdx.y;
  int b = blockIdx.z;
  int bh = b * HEADS + h;
  int myq = w * 16 + l15;             // this lane's q within the tile

  // stage Q tile (64 rows x 64 d), swizzled
#pragma unroll
  for (int it = 0; it < 2; ++it) {
    int row = it * 32 + (t >> 3), ch = t & 7;
    *(u32x4*)&sQ[swz(row, ch * 8)] =
        *(const u32x4*)&Qp[(size_t)(b * SEQ + q0 + row) * E_DIM + h * HD + ch * 8];
  }

  const unsigned long long* mrow = bits + ((size_t)(b * SEQ + q0 + myq) << 5);
  float m_s = NEGF, lsum = 0.f;
  f32x4 o[4] = {};                    // O^T: d = mt*16+quad*4+r, q = myq

  for (int kt = 0; kt < 32; ++kt) {
    int k0 = kt * 64;
    __syncthreads();   // previous tile's sK/sVt reads done
#pragma unroll
    for (int it = 0; it < 2; ++it) {
      int row = it * 32 + (t >> 3), ch = t & 7;
      *(u32x4*)&sK[swz(row, ch * 8)] =
          *(const u32x4*)&Kp[(size_t)(b * SEQ + k0 + row) * E_DIM + h * HD + ch * 8];
      *(u32x4*)&sVt[swz(row, ch * 8)] =
          *(const u32x4*)&Vt[((size_t)bh * HD + row) * SEQ + k0 + ch * 8];
    }
    __syncthreads();

    // S^T: s[nt][r] = score(q=myq, k=nt*16+quad*4+r). A=K rows, B=Q rows.
    f32x4 s[4] = {};
#pragma unroll
    for (int ks = 0; ks < 2; ++ks) {
      bf16x8 qf = *(const bf16x8*)&sQ[swz(myq, ks * 32 + quad * 8)];
#pragma unroll
      for (int nt = 0; nt < 4; ++nt) {
        bf16x8 kf = *(const bf16x8*)&sK[swz(nt * 16 + l15, ks * 32 + quad * 8)];
        s[nt] = __builtin_amdgcn_mfma_f32_16x16x32_bf16(kf, qf, s[nt], 0, 0, 0);
      }
    }

    // mask: one u64 per lane per tile; bit (nt*16 + quad*4 + r)
    unsigned long long wm = mrow[kt];
    unsigned sx = ((unsigned)wm) >> (quad * 4);
    unsigned sy = ((unsigned)(wm >> 32)) >> (quad * 4);
    float sm[4][4];
    float vm = NEGF;
#pragma unroll
    for (int nt = 0; nt < 4; ++nt) {
      unsigned wsel = (nt & 2) ? sy : sx;
      int sh = (nt & 1) ? 16 : 0;
#pragma unroll
      for (int r = 0; r < 4; ++r) {
        bool ok = (wsel >> (sh + r)) & 1u;
        sm[nt][r] = ok ? s[nt][r] : NEGF;   // sentinel: exp underflows to 0
        vm = fmaxf(vm, sm[nt][r]);
      }
    }
    vm = fmaxf(vm, __shfl_xor(vm, 16));
    vm = fmaxf(vm, __shfl_xor(vm, 32));
    float mnew = fmaxf(m_s, vm);
    float alpha = __expf(m_s - mnew);       // flushes any all-masked-prefix garbage
    float ps = 0.f;
#pragma unroll
    for (int nt = 0; nt < 4; ++nt) {
      union { ushort_t u[4]; uint2 v; } pk;
#pragma unroll
      for (int r = 0; r < 4; ++r) {
        float pv = __expf(sm[nt][r] - mnew);
        ps += pv;
        pk.u[r] = f2b(pv);
      }
      *(uint2*)&sP[swz(myq, nt * 16 + quad * 4)] = pk.v;   // 4 consecutive k, 8B
    }
    ps += __shfl_xor(ps, 16);
    ps += __shfl_xor(ps, 32);
    lsum = lsum * alpha + ps;
    m_s = mnew;
#pragma unroll
    for (int mt = 0; mt < 4; ++mt) o[mt] *= alpha;
    __syncthreads();   // sP visible before PV

    // O^T += V^T P^T : A-frag sVt[d][k], B-frag sP[q][k]
#pragma unroll
    for (int ks = 0; ks < 2; ++ks) {
      bf16x8 pf = *(const bf16x8*)&sP[swz(myq, ks * 32 + quad * 8)];
#pragma unroll
      for (int mt = 0; mt < 4; ++mt) {
        bf16x8 vf = *(const bf16x8*)&sVt[swz(mt * 16 + l15, ks * 32 + quad * 8)];
        o[mt] = __builtin_amdgcn_mfma_f32_16x16x32_bf16(vf, pf, o[mt], 0, 0, 0);
      }
    }
  }

  // epilogue: per-lane scalar normalize; fully-masked q -> 0
  float inv = (m_s > -0.9e30f && lsum > 0.f) ? 1.f / lsum : 0.f;
  size_t base = (size_t)(b * SEQ + q0 + myq) * E_DIM + h * HD;
#pragma unroll
  for (int mt = 0; mt < 4; ++mt) {
    union { ushort_t u[4]; uint2 v; } ov;
#pragma unroll
    for (int r = 0; r < 4; ++r) ov.u[r] = f2b(o[mt][r] * inv);
    *(uint2*)&ctx[base + mt * 16 + quad * 4] = ov.v;       // 4 consecutive d, 8B
  }
}

// ---------------- launch ----------------
// fp32 in/out, bf16 internals. ws = 20 MiB: bufA(8) bufB(8) WT(2) bits(2).
// d_out (16 MB fp32) doubles as two 8 MB bf16 slots dlo/dhi.
// Liveness schedule (single stream, race-free):
//   WT <- transposeW4; bits <- pack_mask
//   qn->dlo, kvn->bufA (ln2)
//   qp  = (qn@WTq+bq)*.125 -> dhi
//   kp  = kvn@WTk+bk       -> dlo   [qn dead]
//   vp  = kvn@WTv+bv       -> bufB
//   Vt  = transposeV(vp)   -> bufA  [kvn dead]
//   ctx = attn(qp,kp,Vt)   -> bufB  [vp dead]
//   out = ctx@WTo+bo       -> d_out [qp/kp dead]
extern "C" void kernel_launch(void* const* d_in, const int* in_sizes, int n_in,
                              void* d_out, int out_size, void* d_ws, size_t ws_size,
                              hipStream_t stream) {
  const float* query     = (const float*)d_in[0];
  const float* key_value = (const float*)d_in[1];
  const int*   kv_mask   = (const int*)d_in[2];
  const int*   sp_mask   = (const int*)d_in[3];
  const float* ln_q_g  = (const float*)d_in[4];
  const float* ln_q_b  = (const float*)d_in[5];
  const float* ln_kv_g = (const float*)d_in[6];
  const float* ln_kv_b = (const float*)d_in[7];
  const float* Wq = (const float*)d_in[8];
  const float* bq = (const float*)d_in[9];
  const float* Wk = (const float*)d_in[10];
  const float* bk = (const float*)d_in[11];
  const float* Wv = (const float*)d_in[12];
  const float* bv = (const float*)d_in[13];
  const float* Wo = (const float*)d_in[14];
  const float* bo = (const float*)d_in[15];

  const size_t NB = (size_t)NROWS * E_DIM;       // 4M bf16 elements = 8 MiB
  char* ws = (char*)d_ws;
  ushort_t* bufA = (ushort_t*)ws;                // kvn -> Vt
  ushort_t* bufB = bufA + NB;                    // vp -> ctx
  ushort_t* WTq  = bufB + NB;                    // 4 x 512x512 bf16 = 2 MiB
  ushort_t* WTk = WTq + E_DIM * E_DIM;
  ushort_t* WTv = WTk + E_DIM * E_DIM;
  ushort_t* WTo = WTv + E_DIM * E_DIM;
  unsigned long long* bits = (unsigned long long*)(WTo + E_DIM * E_DIM);  // 2 MiB

  ushort_t* dlo = (ushort_t*)d_out;              // qn, then kp
  ushort_t* dhi = dlo + NB;                      // qp

  transposeW4<<<dim3(16, 16, 4), 256, 0, stream>>>(Wq, Wk, Wv, Wo, WTq);
  pack_mask<<<2048, 256, 0, stream>>>(kv_mask, sp_mask, bits);

  ln2_kernel<<<dim3(2048, 2), 256, 0, stream>>>(query, key_value, ln_q_g, ln_q_b,
                                                ln_kv_g, ln_kv_b, dlo, bufA);

  gemm_bias<ushort_t><<<dim3(64, 8), 256, 0, stream>>>(dlo, WTq, bq, dhi, 0.125f); // qp
  gemm_bias<ushort_t><<<dim3(64, 8), 256, 0, stream>>>(bufA, WTk, bk, dlo, 1.f);   // kp
  gemm_bias<ushort_t><<<dim3(64, 8), 256, 0, stream>>>(bufA, WTv, bv, bufB, 1.f);  // vp

  transposeV<<<dim3(32, HEADS, 4), 256, 0, stream>>>(bufB, bufA);          // Vt

  attn_kernel<<<dim3(32, HEADS, 4), 256, 0, stream>>>(dhi, dlo, bufA, bits, bufB);

  gemm_bias<float><<<dim3(64, 8), 256, 0, stream>>>(bufB, WTo, bo, (float*)d_out, 1.f);
}

// Round 8
// 311.840 us; speedup vs baseline: 2.1112x; 1.0484x over previous
//
#include <hip/hip_runtime.h>
#include <hip/hip_bf16.h>
#include <math.h>

typedef unsigned short ushort_t;
typedef __attribute__((ext_vector_type(8))) __bf16 bf16x8;
typedef __attribute__((ext_vector_type(4))) float f32x4;
typedef __attribute__((ext_vector_type(4))) unsigned int u32x4;

#define E_DIM 512
#define HEADS 8
#define HD 64
#define SEQ 2048
#define NROWS 8192        // B * SEQ
#define NEGF (-1e30f)
#define QSCALE 0.18033688011112042f   // 0.125 * log2(e): scores in log2 domain

static __device__ __forceinline__ unsigned short f2b(float f) {
  unsigned int x;
  __builtin_memcpy(&x, &f, 4);
  x += 0x7fffu + ((x >> 16) & 1u);   // RNE (used only in cold epilogues)
  return (unsigned short)(x >> 16);
}

// XOR-swizzled LDS index for 64-col bf16 tiles (16B chunks) — conflict-free reads.
static __device__ __forceinline__ int swz(int row, int col) {
  return row * 64 + ((((col >> 3) ^ (row & 7)) & 7) << 3) + (col & 7);
}

// Async 16B/lane global->LDS DMA; dest = lds_base + lane*16B (wave-uniform base).
// Caller arranges the swizzle by permuting the per-lane GLOBAL address.
static __device__ __forceinline__ void gl2lds16(const ushort_t* g, ushort_t* s) {
#if __has_builtin(__builtin_amdgcn_global_load_lds)
  __builtin_amdgcn_global_load_lds(
      (const __attribute__((address_space(1))) unsigned int*)(uintptr_t)g,
      (__attribute__((address_space(3))) unsigned int*)(uintptr_t)s,
      16, 0, 0);
#else
  int l = threadIdx.x & 63;
  *(u32x4*)(s + l * 8) = *(const u32x4*)g;
#endif
}

// ---------------- prep: fused transposeW(x4) + pack_mask + 2x LayerNorm ----------------
__launch_bounds__(256)
__global__ void prep_kernel(const float* __restrict__ Wq, const float* __restrict__ Wk,
                            const float* __restrict__ Wv, const float* __restrict__ Wo,
                            ushort_t* __restrict__ WT,
                            const int* __restrict__ kvm, const int* __restrict__ sp,
                            unsigned long long* __restrict__ bits,
                            const float* __restrict__ xq, const float* __restrict__ xkv,
                            const float* __restrict__ gq, const float* __restrict__ bq,
                            const float* __restrict__ gkv, const float* __restrict__ bkv,
                            ushort_t* __restrict__ yq, ushort_t* __restrict__ ykv) {
  int blk = blockIdx.x;
  int t = threadIdx.x;
  if (blk < 1024) {                       // ---- weight transpose+cast: WT[z][n][k]=bf16(W_z[k][n])
    int z = blk >> 8, rem = blk & 255;
    const float* in = (z == 0) ? Wq : (z == 1) ? Wk : (z == 2) ? Wv : Wo;
    ushort_t* o = WT + (size_t)z * E_DIM * E_DIM;
    __shared__ float tile[32 * 33];
    int tx = t & 31, ty = t >> 5;
    int n0 = (rem & 15) * 32, k0 = (rem >> 4) * 32;
#pragma unroll
    for (int i = 0; i < 4; ++i) {
      int k = ty + i * 8;
      tile[k * 33 + tx] = in[(k0 + k) * E_DIM + n0 + tx];
    }
    __syncthreads();
#pragma unroll
    for (int i = 0; i < 4; ++i) {
      int n = ty + i * 8;
      o[(n0 + n) * E_DIM + k0 + tx] = f2b(tile[tx * 33 + n]);
    }
  } else if (blk < 3072) {                // ---- mask pack (ballot, coalesced)
    int w = t >> 6, l = t & 63;
    int row = (blk - 1024) * 4 + w;
    int b = row >> 11;
    const int* sprow = sp + ((size_t)row << 11);
    const int* kvrow = kvm + (b << 11);
    unsigned long long* out = bits + ((size_t)row << 5);
#pragma unroll 4
    for (int it = 0; it < 32; ++it) {
      int k = it * 64 + l;
      unsigned long long m = __ballot(sprow[k] != 0 && kvrow[k] != 0);
      if (l == 0) out[it] = m;
    }
  } else {                                // ---- LayerNorm, both tensors
    int idx = blk - 3072;
    int which = idx >> 11;
    const float* x = which ? xkv : xq;
    const float* g = which ? gkv : gq;
    const float* bb = which ? bkv : bq;
    ushort_t* y = which ? ykv : yq;
    int w = t >> 6, l = t & 63;
    int row = (idx & 2047) * 4 + w;
    f32x4 x0 = *(const f32x4*)&x[row * E_DIM + l * 8];
    f32x4 x1 = *(const f32x4*)&x[row * E_DIM + l * 8 + 4];
    float xf[8], s = 0.f, ss = 0.f;
#pragma unroll
    for (int j = 0; j < 8; ++j) {
      xf[j] = (j < 4) ? x0[j] : x1[j - 4];
      s += xf[j];
      ss += xf[j] * xf[j];
    }
#pragma unroll
    for (int off = 32; off > 0; off >>= 1) {
      s += __shfl_xor(s, off);
      ss += __shfl_xor(ss, off);
    }
    float mu = s * (1.f / 512.f);
    float var = fmaxf(ss * (1.f / 512.f) - mu * mu, 0.f);
    float rs = rsqrtf(var + 1e-5f);
    f32x4 g0 = *(const f32x4*)&g[l * 8];
    f32x4 g1 = *(const f32x4*)&g[l * 8 + 4];
    f32x4 b0 = *(const f32x4*)&bb[l * 8];
    f32x4 b1 = *(const f32x4*)&bb[l * 8 + 4];
#pragma unroll
    for (int j = 0; j < 8; ++j) {
      float gv = (j < 4) ? g0[j] : g1[j - 4];
      float bv = (j < 4) ? b0[j] : b1[j - 4];
      y[row * E_DIM + l * 8 + j] = f2b((xf[j] - mu) * rs * gv + bv);
    }
  }
}

// ---------------- V transpose: vp[b][k][h*64+d] -> Vt[((b*8+h)*64+d)*2048 + k] ----------------
__launch_bounds__(256)
__global__ void transposeV(const ushort_t* __restrict__ vp, ushort_t* __restrict__ Vt) {
  __shared__ ushort_t tile[64][72];
  int t = threadIdx.x;
  int k0 = blockIdx.x * 64, h = blockIdx.y, b = blockIdx.z;
#pragma unroll
  for (int it = 0; it < 2; ++it) {
    int row = it * 32 + (t >> 3), col = (t & 7) * 8;
    *(u32x4*)&tile[row][col] =
        *(const u32x4*)&vp[(size_t)(b * SEQ + k0 + row) * E_DIM + h * HD + col];
  }
  __syncthreads();
#pragma unroll
  for (int it = 0; it < 2; ++it) {
    int d = it * 32 + (t >> 3), kc = (t & 7) * 8;
    union { ushort_t u[8]; u32x4 v; } o;
#pragma unroll
    for (int j = 0; j < 8; ++j) o.u[j] = tile[kc + j][d];
    *(u32x4*)&Vt[((size_t)(b * HEADS + h) * HD + d) * SEQ + k0 + kc] = o.v;
  }
}

// ---------------- GEMM core: C[128,64-tile] = (A @ WT^T + bias) * scale ----------------
// BK=64, global_load_lds staging (lane-permuted addresses realize the swizzle).
template <typename OUT_T>
static __device__ __forceinline__ void gemm_core(ushort_t* lA, ushort_t* lB,
                                                 const ushort_t* __restrict__ A,
                                                 const ushort_t* __restrict__ WT,
                                                 const float* __restrict__ bias,
                                                 OUT_T* __restrict__ C, float scale,
                                                 int m0, int n0) {
  int t = threadIdx.x, w = t >> 6, l = t & 63;
  int quad = l >> 4, l15 = l & 15;
  int wm_ = w >> 1, wn_ = w & 1;
  int csrc = ((l & 7) ^ (l >> 3)) * 8;   // swizzle folded into per-lane global column
  int rln = l >> 3;

  f32x4 acc[4][2] = {};
  for (int kk = 0; kk < E_DIM; kk += 64) {
    __syncthreads();
#pragma unroll
    for (int i = 0; i < 4; ++i) {
      int r0 = i * 32 + w * 8;
      gl2lds16(&A[(size_t)(m0 + r0 + rln) * E_DIM + kk + csrc], &lA[r0 * 64]);
    }
#pragma unroll
    for (int i = 0; i < 2; ++i) {
      int r0 = i * 32 + w * 8;
      gl2lds16(&WT[(size_t)(n0 + r0 + rln) * E_DIM + kk + csrc], &lB[r0 * 64]);
    }
    __syncthreads();
#pragma unroll
    for (int ks = 0; ks < 2; ++ks) {
      bf16x8 af[4], bf[2];
#pragma unroll
      for (int mt = 0; mt < 4; ++mt)
        af[mt] = *(const bf16x8*)&lA[swz(wm_ * 64 + mt * 16 + l15, ks * 32 + quad * 8)];
#pragma unroll
      for (int nt = 0; nt < 2; ++nt)
        bf[nt] = *(const bf16x8*)&lB[swz(wn_ * 32 + nt * 16 + l15, ks * 32 + quad * 8)];
#pragma unroll
      for (int mt = 0; mt < 4; ++mt)
#pragma unroll
        for (int nt = 0; nt < 2; ++nt)
          acc[mt][nt] = __builtin_amdgcn_mfma_f32_16x16x32_bf16(af[mt], bf[nt], acc[mt][nt], 0, 0, 0);
    }
  }
#pragma unroll
  for (int nt = 0; nt < 2; ++nt) {
    int col = n0 + wn_ * 32 + nt * 16 + l15;
    float bv = bias[col];
#pragma unroll
    for (int mt = 0; mt < 4; ++mt) {
#pragma unroll
      for (int r = 0; r < 4; ++r) {
        int rowm = m0 + wm_ * 64 + mt * 16 + quad * 4 + r;   // C/D: col=lane&15, row=quad*4+r
        float val = (acc[mt][nt][r] + bv) * scale;
        if constexpr (sizeof(OUT_T) == 2)
          C[rowm * E_DIM + col] = f2b(val);
        else
          C[rowm * E_DIM + col] = val;
      }
    }
  }
}

template <typename OUT_T>
__launch_bounds__(256)
__global__ void gemm_bias(const ushort_t* __restrict__ A, const ushort_t* __restrict__ WT,
                          const float* __restrict__ bias, OUT_T* __restrict__ C, float scale) {
  __shared__ ushort_t lA[128 * 64];
  __shared__ ushort_t lB[64 * 64];
  gemm_core<OUT_T>(lA, lB, A, WT, bias, C, scale, blockIdx.x * 128, blockIdx.y * 64);
}

// two independent projections in one dispatch (z selects); inputs/outputs disjoint
__launch_bounds__(256)
__global__ void gemm_proj2(const ushort_t* A0, const ushort_t* W0, const float* b0, ushort_t* C0, float s0,
                           const ushort_t* A1, const ushort_t* W1, const float* b1, ushort_t* C1, float s1) {
  __shared__ ushort_t lA[128 * 64];
  __shared__ ushort_t lB[64 * 64];
  int m0 = blockIdx.x * 128, n0 = blockIdx.y * 64;
  if (blockIdx.z == 0) gemm_core<ushort_t>(lA, lB, A0, W0, b0, C0, s0, m0, n0);
  else                 gemm_core<ushort_t>(lA, lB, A1, W1, b1, C1, s1, m0, n0);
}

// ---------------- flash attention, transposed-S, log2-domain softmax ----------------
// Qp pre-scaled by 0.125*log2e. Vt is [b][h][d][k]. bits = packed (kv & sparse) mask.
// Lane owns one q (myq = w*16+l15), 16 scores/tile (k = nt*16+quad*4+r).
__launch_bounds__(256)
__global__ void attn_kernel(const ushort_t* __restrict__ Qp, const ushort_t* __restrict__ Kp,
                            const ushort_t* __restrict__ Vt,
                            const unsigned long long* __restrict__ bits,
                            ushort_t* __restrict__ ctx) {
  __shared__ ushort_t sQ[64 * 64];
  __shared__ ushort_t sK[64 * 64];
  __shared__ ushort_t sVt[64 * 64];   // [d][k]
  __shared__ ushort_t sP[64 * 64];    // [q][k]
  int t = threadIdx.x, w = t >> 6, l = t & 63;
  int quad = l >> 4, l15 = l & 15;
  int q0 = blockIdx.x * 64;
  int h = blockIdx.y;
  int b = blockIdx.z;
  int bh = b * HEADS + h;
  int myq = w * 16 + l15;
  int csrc = ((l & 7) ^ (l >> 3)) * 8;
  int rln = l >> 3;

  // stage Q (async DMA; drained by the loop's first barrier)
#pragma unroll
  for (int it = 0; it < 2; ++it) {
    int r0 = it * 32 + w * 8;
    gl2lds16(&Qp[(size_t)(b * SEQ + q0 + r0 + rln) * E_DIM + h * HD + csrc], &sQ[r0 * 64]);
  }

  const unsigned long long* mrow = bits + ((size_t)(b * SEQ + q0 + myq) << 5);
  float m_s = NEGF, lsum = 0.f;
  f32x4 o[4] = {};

  for (int kt = 0; kt < 32; ++kt) {
    int k0 = kt * 64;
    __syncthreads();   // prev tile's sK/sVt reads done
#pragma unroll
    for (int it = 0; it < 2; ++it) {
      int r0 = it * 32 + w * 8;
      gl2lds16(&Kp[(size_t)(b * SEQ + k0 + r0 + rln) * E_DIM + h * HD + csrc], &sK[r0 * 64]);
      gl2lds16(&Vt[((size_t)bh * HD + r0 + rln) * SEQ + k0 + csrc], &sVt[r0 * 64]);
    }
    __syncthreads();   // DMA drained

    // S^T: s[nt][r] = log2-score(q=myq, k=nt*16+quad*4+r)
    f32x4 s[4] = {};
#pragma unroll
    for (int ks = 0; ks < 2; ++ks) {
      bf16x8 qf = *(const bf16x8*)&sQ[swz(myq, ks * 32 + quad * 8)];
#pragma unroll
      for (int nt = 0; nt < 4; ++nt) {
        bf16x8 kf = *(const bf16x8*)&sK[swz(nt * 16 + l15, ks * 32 + quad * 8)];
        s[nt] = __builtin_amdgcn_mfma_f32_16x16x32_bf16(kf, qf, s[nt], 0, 0, 0);
      }
    }

    unsigned long long wmask = mrow[kt];
    unsigned sx = ((unsigned)wmask) >> (quad * 4);
    unsigned sy = ((unsigned)(wmask >> 32)) >> (quad * 4);
    float sm[4][4];
    float vm = NEGF;
#pragma unroll
    for (int nt = 0; nt < 4; ++nt) {
      unsigned wsel = (nt & 2) ? sy : sx;
      int sh = (nt & 1) ? 16 : 0;
#pragma unroll
      for (int r = 0; r < 4; ++r) {
        bool ok = (wsel >> (sh + r)) & 1u;
        sm[nt][r] = ok ? s[nt][r] : NEGF;
        vm = fmaxf(vm, sm[nt][r]);
      }
    }
    vm = fmaxf(vm, __shfl_xor(vm, 16));
    vm = fmaxf(vm, __shfl_xor(vm, 32));
    float mnew = fmaxf(m_s, vm);
    float alpha = exp2f(m_s - mnew);    // all-masked-prefix self-heals (flushed on first valid)
    float ps = 0.f;
#pragma unroll
    for (int nt = 0; nt < 4; ++nt) {
      union { ushort_t u[4]; uint2 v; } pk;
#pragma unroll
      for (int r = 0; r < 4; ++r) {
        float pv = exp2f(sm[nt][r] - mnew);
        unsigned short uu = (unsigned short)(__float_as_uint(pv) >> 16);  // trunc-to-bf16
        pk.u[r] = uu;
        ps += __uint_as_float(((unsigned)uu) << 16);   // lsum consistent with stored P
      }
      *(uint2*)&sP[swz(myq, nt * 16 + quad * 4)] = pk.v;
    }
    ps += __shfl_xor(ps, 16);
    ps += __shfl_xor(ps, 32);
    lsum = lsum * alpha + ps;
    m_s = mnew;
#pragma unroll
    for (int mt = 0; mt < 4; ++mt) o[mt] *= alpha;
    __syncthreads();   // sP visible before PV

    // O^T += V^T P^T
#pragma unroll
    for (int ks = 0; ks < 2; ++ks) {
      bf16x8 pf = *(const bf16x8*)&sP[swz(myq, ks * 32 + quad * 8)];
#pragma unroll
      for (int mt = 0; mt < 4; ++mt) {
        bf16x8 vf = *(const bf16x8*)&sVt[swz(mt * 16 + l15, ks * 32 + quad * 8)];
        o[mt] = __builtin_amdgcn_mfma_f32_16x16x32_bf16(vf, pf, o[mt], 0, 0, 0);
      }
    }
  }

  float inv = (m_s > -0.9e30f && lsum > 0.f) ? 1.f / lsum : 0.f;
  size_t base = (size_t)(b * SEQ + q0 + myq) * E_DIM + h * HD;
#pragma unroll
  for (int mt = 0; mt < 4; ++mt) {
    union { ushort_t u[4]; uint2 v; } ov;
#pragma unroll
    for (int r = 0; r < 4; ++r) ov.u[r] = f2b(o[mt][r] * inv);
    *(uint2*)&ctx[base + mt * 16 + quad * 4] = ov.v;
  }
}

// ---------------- launch ----------------
// fp32 in/out, bf16 internals. ws = 20 MiB: bufA(8) bufB(8) WT(2) bits(2).
// d_out (16 MB fp32) = two 8 MB bf16 slots dlo/dhi. 6 dispatches:
//   1 prep:  WT, bits, qn->dlo, kvn->bufA
//   2 proj2: qp=(qn@WTq+bq)*QSCALE -> dhi ; vp=kvn@WTv+bv -> bufB   (in/out disjoint)
//   3 kp:    kvn@WTk+bk -> dlo   [qn dead]
//   4 transposeV: bufB -> bufA   [kvn dead]
//   5 attn:  (dhi,dlo,bufA,bits) -> bufB   [vp dead]
//   6 out:   bufB@WTo+bo -> d_out fp32     [qp/kp dead]
extern "C" void kernel_launch(void* const* d_in, const int* in_sizes, int n_in,
                              void* d_out, int out_size, void* d_ws, size_t ws_size,
                              hipStream_t stream) {
  const float* query     = (const float*)d_in[0];
  const float* key_value = (const float*)d_in[1];
  const int*   kv_mask   = (const int*)d_in[2];
  const int*   sp_mask   = (const int*)d_in[3];
  const float* ln_q_g  = (const float*)d_in[4];
  const float* ln_q_b  = (const float*)d_in[5];
  const float* ln_kv_g = (const float*)d_in[6];
  const float* ln_kv_b = (const float*)d_in[7];
  const float* Wq = (const float*)d_in[8];
  const float* bq = (const float*)d_in[9];
  const float* Wk = (const float*)d_in[10];
  const float* bk = (const float*)d_in[11];
  const float* Wv = (const float*)d_in[12];
  const float* bv = (const float*)d_in[13];
  const float* Wo = (const float*)d_in[14];
  const float* bo = (const float*)d_in[15];

  const size_t NB = (size_t)NROWS * E_DIM;       // 8 MiB bf16 slot
  char* ws = (char*)d_ws;
  ushort_t* bufA = (ushort_t*)ws;                // kvn -> Vt
  ushort_t* bufB = bufA + NB;                    // vp -> ctx
  ushort_t* WT   = bufB + NB;                    // 4 x 512x512 bf16 = 2 MiB
  ushort_t* WTq = WT;
  ushort_t* WTk = WTq + E_DIM * E_DIM;
  ushort_t* WTv = WTk + E_DIM * E_DIM;
  ushort_t* WTo = WTv + E_DIM * E_DIM;
  unsigned long long* bits = (unsigned long long*)(WTo + E_DIM * E_DIM);  // 2 MiB

  ushort_t* dlo = (ushort_t*)d_out;              // qn, then kp
  ushort_t* dhi = dlo + NB;                      // qp

  prep_kernel<<<7168, 256, 0, stream>>>(Wq, Wk, Wv, Wo, WT, kv_mask, sp_mask, bits,
                                        query, key_value, ln_q_g, ln_q_b, ln_kv_g, ln_kv_b,
                                        dlo, bufA);

  gemm_proj2<<<dim3(64, 8, 2), 256, 0, stream>>>(dlo, WTq, bq, dhi, QSCALE,
                                                 bufA, WTv, bv, bufB, 1.f);

  gemm_bias<ushort_t><<<dim3(64, 8), 256, 0, stream>>>(bufA, WTk, bk, dlo, 1.f);   // kp

  transposeV<<<dim3(32, HEADS, 4), 256, 0, stream>>>(bufB, bufA);                  // Vt

  attn_kernel<<<dim3(32, HEADS, 4), 256, 0, stream>>>(dhi, dlo, bufA, bits, bufB);

  gemm_bias<float><<<dim3(64, 8), 256, 0, stream>>>(bufB, WTo, bo, (float*)d_out, 1.f);
}